// Round 5
// baseline (1370.400 us; speedup 1.0000x reference)
//
#include <hip/hip_runtime.h>
#include <math.h>

typedef unsigned int u32;
typedef int iv4 __attribute__((ext_vector_type(4)));

#define BKT_BITS 12
#define BKT_SIZE 4096
#define NBMAX    256
#define DEPTH    112         // LDS staging depth per bucket (mean ~67/tile)
#define BIN_T    512
#define TILE     16384       // edges per bin block = BIN_T * 8 rounds * 4/int4

// ---------------- fast path ----------------

__global__ void zero_u32(u32* __restrict__ p, int n) {
    int i = blockIdx.x * blockDim.x + threadIdx.x;
    if (i < n) p[i] = 0u;
}

__global__ void count_kernel(const int* __restrict__ dst, u32* __restrict__ gcount, int E, int NB) {
    __shared__ u32 h[NBMAX];
    for (int t = threadIdx.x; t < NBMAX; t += blockDim.x) h[t] = 0u;
    __syncthreads();
    int nvec = E >> 2;
    for (int v = blockIdx.x * blockDim.x + threadIdx.x; v < nvec; v += gridDim.x * blockDim.x) {
        iv4 d = __builtin_nontemporal_load(reinterpret_cast<const iv4*>(dst) + v);
        atomicAdd(&h[((u32)d.x) >> BKT_BITS], 1u);
        atomicAdd(&h[((u32)d.y) >> BKT_BITS], 1u);
        atomicAdd(&h[((u32)d.z) >> BKT_BITS], 1u);
        atomicAdd(&h[((u32)d.w) >> BKT_BITS], 1u);
    }
    if (blockIdx.x == 0) {
        for (int e = (nvec << 2) + threadIdx.x; e < E; e += blockDim.x)
            atomicAdd(&h[((u32)dst[e]) >> BKT_BITS], 1u);
    }
    __syncthreads();
    for (int t = threadIdx.x; t < NB; t += blockDim.x)
        if (h[t]) atomicAdd(&gcount[t], h[t]);
}

// 1 block: 64-aligned exclusive scan of per-bucket capacities -> base, cursor
__global__ void scan_kernel(const u32* __restrict__ gcount, u32* __restrict__ gbase,
                            u32* __restrict__ gcursor, int NB) {
    __shared__ u32 sc[NBMAX];
    int t = threadIdx.x;
    u32 cap = 0u;
    if (t < NB) cap = (gcount[t] + 63u) & ~63u;
    sc[t] = cap;
    __syncthreads();
    for (int off = 1; off < NBMAX; off <<= 1) {
        u32 v = (t >= off) ? sc[t - off] : 0u;
        __syncthreads();
        sc[t] += v;
        __syncthreads();
    }
    if (t < NB) {
        u32 base = sc[t] - cap;
        gbase[t]   = base;
        gcursor[t] = base;
    }
}

__global__ void __launch_bounds__(BIN_T)
bin_kernel(const int* __restrict__ src, const int* __restrict__ dst,
           u32* __restrict__ recs, u32* __restrict__ gcursor, int E, int NB) {
    __shared__ u32 stag[NBMAX * DEPTH];   // 112 KB
    __shared__ u32 scnt[NBMAX];
    for (int t = threadIdx.x; t < NBMAX; t += BIN_T) scnt[t] = 0u;
    __syncthreads();
    int base = blockIdx.x * TILE;
#pragma unroll
    for (int r = 0; r < TILE / (BIN_T * 4); ++r) {
        int v  = (base >> 2) + r * BIN_T + threadIdx.x;   // int4 index
        int e0 = v << 2;
        if (e0 + 3 < E) {
            iv4 s4 = __builtin_nontemporal_load(reinterpret_cast<const iv4*>(src) + v);
            iv4 d4 = __builtin_nontemporal_load(reinterpret_cast<const iv4*>(dst) + v);
#pragma unroll
            for (int k = 0; k < 4; ++k) {
                u32 ss = (u32)s4[k], dd = (u32)d4[k];
                u32 b   = dd >> BKT_BITS;
                u32 rec = (ss << BKT_BITS) | (dd & (BKT_SIZE - 1));
                u32 slot = atomicAdd(&scnt[b], 1u);
                if (slot < DEPTH) stag[b * DEPTH + slot] = rec;
                else { u32 g = atomicAdd(&gcursor[b], 1u); recs[g] = rec; }  // statistically never
            }
        } else if (e0 < E) {
            for (int e = e0; e < E && e < e0 + 4; ++e) {
                u32 ss = (u32)src[e], dd = (u32)dst[e];
                u32 b   = dd >> BKT_BITS;
                u32 rec = (ss << BKT_BITS) | (dd & (BKT_SIZE - 1));
                u32 slot = atomicAdd(&scnt[b], 1u);
                if (slot < DEPTH) stag[b * DEPTH + slot] = rec;
                else { u32 g = atomicAdd(&gcursor[b], 1u); recs[g] = rec; }
            }
        }
    }
    __syncthreads();
    // wave-cooperative coalesced flush: wave w flushes buckets w, w+8, ...
    int wave = threadIdx.x >> 6, lane = threadIdx.x & 63;
    for (int b = wave; b < NB; b += BIN_T / 64) {
        u32 c = scnt[b]; if (c > DEPTH) c = DEPTH;
        u32 g = 0u;
        if (lane == 0 && c) g = atomicAdd(&gcursor[b], c);
        g = __shfl(g, 0);
        for (u32 k = lane; k < c; k += 64)
            recs[g + k] = stag[b * DEPTH + k];   // contiguous across lanes
    }
}

// one block owns one bucket: histogram -> deg -> dinv, s. No global atomics.
__global__ void __launch_bounds__(1024)
degnode_kernel(const u32* __restrict__ recs, const u32* __restrict__ gbase,
               const u32* __restrict__ gcount, const float* __restrict__ x,
               const float* __restrict__ W, float* __restrict__ dinv,
               float* __restrict__ s, int N) {
    __shared__ u32 cnt[BKT_SIZE];   // 16 KB
    int b = blockIdx.x;
    for (int j = threadIdx.x; j < BKT_SIZE; j += 1024) cnt[j] = 0u;
    __syncthreads();
    u32 c = gcount[b], base = gbase[b];
    for (u32 k = threadIdx.x; k < c; k += 1024) {
        u32 rec = __builtin_nontemporal_load(recs + base + k);
        atomicAdd(&cnt[rec & (BKT_SIZE - 1)], 1u);
    }
    __syncthreads();
    int nid0 = b << BKT_BITS;
    float W0 = W[0];
    for (int j = threadIdx.x; j < BKT_SIZE; j += 1024) {
        int nid = nid0 + j;
        if (nid < N) {
            float di = rsqrtf((float)(cnt[j] + 1u));
            dinv[nid] = di;
            s[nid] = x[nid] * W0 * di;
        }
    }
}

// one block owns one bucket: gather s[src], LDS accumulate, sigmoid, write out.
__global__ void __launch_bounds__(1024)
aggout_kernel(const u32* __restrict__ recs, const u32* __restrict__ gbase,
              const u32* __restrict__ gcount, const float* __restrict__ s,
              const float* __restrict__ dinv, const float* __restrict__ bb,
              float* __restrict__ out, int N) {
    __shared__ float acc[BKT_SIZE];  // 16 KB
    int b = blockIdx.x;
    for (int j = threadIdx.x; j < BKT_SIZE; j += 1024) acc[j] = 0.0f;
    __syncthreads();
    u32 c = gcount[b], base = gbase[b];
    for (u32 k = threadIdx.x; k < c; k += 1024) {
        u32 rec = __builtin_nontemporal_load(recs + base + k);
        atomicAdd(&acc[rec & (BKT_SIZE - 1)], s[rec >> BKT_BITS]);  // LDS f32 atomic
    }
    __syncthreads();
    int nid0 = b << BKT_BITS;
    float b0 = bb[0];
    for (int j = threadIdx.x; j < BKT_SIZE; j += 1024) {
        int nid = nid0 + j;
        if (nid < N) {
            float z = dinv[nid] * (acc[j] + s[nid]) + b0;
            out[nid] = 1.0f / (1.0f + expf(-z));
        }
    }
}

// ---------------- fallback path ----------------
__global__ void zero_kernel(int* __restrict__ p, int n) {
    int i = blockIdx.x * blockDim.x + threadIdx.x;
    if (i < n) p[i] = 0;
}
__global__ void deg_kernel(const int* __restrict__ dst, int* __restrict__ deg, int E) {
    int i = (blockIdx.x * blockDim.x + threadIdx.x) * 4;
    if (i + 3 < E) {
        int4 d = *reinterpret_cast<const int4*>(dst + i);
        atomicAdd(&deg[d.x], 1); atomicAdd(&deg[d.y], 1);
        atomicAdd(&deg[d.z], 1); atomicAdd(&deg[d.w], 1);
    } else {
        for (int k = i; k < E; ++k) atomicAdd(&deg[dst[k]], 1);
    }
}
__global__ void node_kernel(const float* __restrict__ x, const int* __restrict__ deg,
                            const float* __restrict__ W, float* __restrict__ s,
                            float* __restrict__ dinv, float* __restrict__ acc, int N) {
    int i = blockIdx.x * blockDim.x + threadIdx.x;
    if (i < N) {
        float di = rsqrtf((float)(deg[i] + 1));
        float si = x[i] * W[0] * di;
        dinv[i] = di; s[i] = si; acc[i] = si;
    }
}
__global__ void scatter_kernel(const int* __restrict__ src, const int* __restrict__ dst,
                               const float* __restrict__ s, float* __restrict__ acc, int E) {
    int i = (blockIdx.x * blockDim.x + threadIdx.x) * 4;
    if (i + 3 < E) {
        int4 sv = *reinterpret_cast<const int4*>(src + i);
        int4 dv = *reinterpret_cast<const int4*>(dst + i);
        atomicAdd(&acc[dv.x], s[sv.x]); atomicAdd(&acc[dv.y], s[sv.y]);
        atomicAdd(&acc[dv.z], s[sv.z]); atomicAdd(&acc[dv.w], s[sv.w]);
    } else {
        for (int k = i; k < E; ++k) atomicAdd(&acc[dst[k]], s[src[k]]);
    }
}
__global__ void out_kernel(const float* __restrict__ acc, const float* __restrict__ dinv,
                           const float* __restrict__ b, float* __restrict__ out, int N) {
    int i = blockIdx.x * blockDim.x + threadIdx.x;
    if (i < N) {
        float z = dinv[i] * acc[i] + b[0];
        out[i] = 1.0f / (1.0f + expf(-z));
    }
}

extern "C" void kernel_launch(void* const* d_in, const int* in_sizes, int n_in,
                              void* d_out, int out_size, void* d_ws, size_t ws_size,
                              hipStream_t stream) {
    const int N = in_sizes[0];
    const int E = in_sizes[1] / 2;
    const float* x  = (const float*)d_in[0];
    const int*   ei = (const int*)d_in[1];
    const float* W  = (const float*)d_in[2];
    const float* b  = (const float*)d_in[3];
    float* out = (float*)d_out;

    const int* srcp = ei;
    const int* dstp = ei + E;
    const int T = 256;

    const int NB = (N + BKT_SIZE - 1) >> BKT_BITS;          // 245 for N=1M
    const size_t recCap = (size_t)E + (size_t)NB * 64;      // alignment slack
    // u32-unit layout: recs | gbase | gcursor | gcount | dinv | s
    const size_t need = (recCap + 3 * (size_t)NB + 2 * (size_t)N) * 4;

    if (N <= (1 << 20) && NB <= NBMAX && ws_size >= need) {
        u32* p = (u32*)d_ws;
        u32*   recs    = p;           p += recCap;
        u32*   gbase   = p;           p += NB;
        u32*   gcursor = p;           p += NB;
        u32*   gcount  = p;           p += NB;
        float* dinv    = (float*)p;   p += N;
        float* s       = (float*)p;

        zero_u32<<<1, T, 0, stream>>>(gcount, NB);
        count_kernel<<<1024, T, 0, stream>>>(dstp, gcount, E, NB);
        scan_kernel<<<1, T, 0, stream>>>(gcount, gbase, gcursor, NB);
        bin_kernel<<<(E + TILE - 1) / TILE, BIN_T, 0, stream>>>(srcp, dstp, recs, gcursor, E, NB);
        degnode_kernel<<<NB, 1024, 0, stream>>>(recs, gbase, gcount, x, W, dinv, s, N);
        aggout_kernel<<<NB, 1024, 0, stream>>>(recs, gbase, gcount, s, dinv, b, out, N);
    } else {
        char* ws = (char*)d_ws;
        int*   deg  = (int*)ws;
        float* s    = (float*)(ws + (size_t)N * 4);
        float* dinv = (float*)(ws + (size_t)N * 8);
        float* acc  = (float*)deg;
        const int blocksN = (N + T - 1) / T;
        const int blocksE = ((E + 3) / 4 + T - 1) / T;
        zero_kernel<<<blocksN, T, 0, stream>>>(deg, N);
        deg_kernel<<<blocksE, T, 0, stream>>>(dstp, deg, E);
        node_kernel<<<blocksN, T, 0, stream>>>(x, deg, W, s, dinv, acc, N);
        scatter_kernel<<<blocksE, T, 0, stream>>>(srcp, dstp, s, acc, E);
        out_kernel<<<blocksN, T, 0, stream>>>(acc, dinv, b, out, N);
    }
}

// Round 6
// 786.666 us; speedup vs baseline: 1.7420x; 1.7420x over previous
//
#include <hip/hip_runtime.h>
#include <math.h>

typedef unsigned int u32;
typedef int iv4 __attribute__((ext_vector_type(4)));

#define BKT_BITS 12
#define BKT_SIZE 4096
#define NBMAX    256
#define DEPTH    32          // LDS staging depth per bucket (mean ~16.7/tile)
#define BIN_T    256
#define TILE     4096        // edges per bin block  (4 rounds x 256 thr x int4)
// bin LDS = 256*32*4 + 1KB = 33 KB -> 4 blocks/CU, 41% occ (measured best, r4)

// ---------------- fast path ----------------

__global__ void zero_u32(u32* __restrict__ p, int n) {
    int i = blockIdx.x * blockDim.x + threadIdx.x;
    if (i < n) p[i] = 0u;
}

__global__ void count_kernel(const int* __restrict__ dst, u32* __restrict__ gcount, int E, int NB) {
    __shared__ u32 h[NBMAX];
    for (int t = threadIdx.x; t < NBMAX; t += blockDim.x) h[t] = 0u;
    __syncthreads();
    int nvec = E >> 2;
    for (int v = blockIdx.x * blockDim.x + threadIdx.x; v < nvec; v += gridDim.x * blockDim.x) {
        iv4 d = __builtin_nontemporal_load(reinterpret_cast<const iv4*>(dst) + v);
        atomicAdd(&h[((u32)d.x) >> BKT_BITS], 1u);
        atomicAdd(&h[((u32)d.y) >> BKT_BITS], 1u);
        atomicAdd(&h[((u32)d.z) >> BKT_BITS], 1u);
        atomicAdd(&h[((u32)d.w) >> BKT_BITS], 1u);
    }
    if (blockIdx.x == 0) {
        for (int e = (nvec << 2) + threadIdx.x; e < E; e += blockDim.x)
            atomicAdd(&h[((u32)dst[e]) >> BKT_BITS], 1u);
    }
    __syncthreads();
    for (int t = threadIdx.x; t < NB; t += blockDim.x)
        if (h[t]) atomicAdd(&gcount[t], h[t]);
}

// 1 block: 64-aligned exclusive scan of per-bucket capacities -> base, cursor
__global__ void scan_kernel(const u32* __restrict__ gcount, u32* __restrict__ gbase,
                            u32* __restrict__ gcursor, int NB) {
    __shared__ u32 sc[NBMAX];
    int t = threadIdx.x;
    u32 cap = 0u;
    if (t < NB) cap = (gcount[t] + 63u) & ~63u;
    sc[t] = cap;
    __syncthreads();
    for (int off = 1; off < NBMAX; off <<= 1) {
        u32 v = (t >= off) ? sc[t - off] : 0u;
        __syncthreads();
        sc[t] += v;
        __syncthreads();
    }
    if (t < NB) {
        u32 base = sc[t] - cap;
        gbase[t]   = base;
        gcursor[t] = base;
    }
}

__global__ void __launch_bounds__(BIN_T)
bin_kernel(const int* __restrict__ src, const int* __restrict__ dst,
           u32* __restrict__ recs, u32* __restrict__ gcursor, int E, int NB) {
    __shared__ u32 stag[NBMAX * DEPTH];   // 32 KB
    __shared__ u32 scnt[NBMAX];
    for (int t = threadIdx.x; t < NBMAX; t += BIN_T) scnt[t] = 0u;
    __syncthreads();
    int base = blockIdx.x * TILE;
#pragma unroll
    for (int r = 0; r < TILE / (BIN_T * 4); ++r) {
        int v  = (base >> 2) + r * BIN_T + threadIdx.x;   // int4 index
        int e0 = v << 2;
        if (e0 + 3 < E) {
            iv4 s4 = __builtin_nontemporal_load(reinterpret_cast<const iv4*>(src) + v);
            iv4 d4 = __builtin_nontemporal_load(reinterpret_cast<const iv4*>(dst) + v);
#pragma unroll
            for (int k = 0; k < 4; ++k) {
                u32 ss = (u32)s4[k], dd = (u32)d4[k];
                u32 b   = dd >> BKT_BITS;
                u32 rec = (ss << BKT_BITS) | (dd & (BKT_SIZE - 1));
                u32 slot = atomicAdd(&scnt[b], 1u);
                if (slot < DEPTH) stag[b * DEPTH + slot] = rec;
                else { u32 g = atomicAdd(&gcursor[b], 1u); recs[g] = rec; }  // rare
            }
        } else if (e0 < E) {
            for (int e = e0; e < E && e < e0 + 4; ++e) {
                u32 ss = (u32)src[e], dd = (u32)dst[e];
                u32 b   = dd >> BKT_BITS;
                u32 rec = (ss << BKT_BITS) | (dd & (BKT_SIZE - 1));
                u32 slot = atomicAdd(&scnt[b], 1u);
                if (slot < DEPTH) stag[b * DEPTH + slot] = rec;
                else { u32 g = atomicAdd(&gcursor[b], 1u); recs[g] = rec; }
            }
        }
    }
    __syncthreads();
    // thread t flushes bucket t (round-4 measured-good flush)
    int t = threadIdx.x;
    if (t < NB) {
        u32 c = scnt[t]; if (c > DEPTH) c = DEPTH;
        if (c > 0u) {
            u32 g = atomicAdd(&gcursor[t], c);
            for (u32 k = 0; k < c; ++k) recs[g + k] = stag[t * DEPTH + k];
        }
    }
}

// one block owns one bucket: histogram -> deg -> dinv, s. No global atomics.
__global__ void __launch_bounds__(1024)
degnode_kernel(const u32* __restrict__ recs, const u32* __restrict__ gbase,
               const u32* __restrict__ gcount, const float* __restrict__ x,
               const float* __restrict__ W, float* __restrict__ dinv,
               float* __restrict__ s, int N) {
    __shared__ u32 cnt[BKT_SIZE];   // 16 KB
    int b = blockIdx.x;
    for (int j = threadIdx.x; j < BKT_SIZE; j += 1024) cnt[j] = 0u;
    __syncthreads();
    u32 c = gcount[b], base = gbase[b];
    for (u32 k = threadIdx.x; k < c; k += 1024) {
        u32 rec = __builtin_nontemporal_load(recs + base + k);
        atomicAdd(&cnt[rec & (BKT_SIZE - 1)], 1u);
    }
    __syncthreads();
    int nid0 = b << BKT_BITS;
    float W0 = W[0];
    for (int j = threadIdx.x; j < BKT_SIZE; j += 1024) {
        int nid = nid0 + j;
        if (nid < N) {
            float di = rsqrtf((float)(cnt[j] + 1u));
            dinv[nid] = di;
            s[nid] = x[nid] * W0 * di;
        }
    }
}

// one block owns one bucket: gather s[src], LDS accumulate, sigmoid, write out.
__global__ void __launch_bounds__(1024)
aggout_kernel(const u32* __restrict__ recs, const u32* __restrict__ gbase,
              const u32* __restrict__ gcount, const float* __restrict__ s,
              const float* __restrict__ dinv, const float* __restrict__ bb,
              float* __restrict__ out, int N) {
    __shared__ float acc[BKT_SIZE];  // 16 KB
    int b = blockIdx.x;
    for (int j = threadIdx.x; j < BKT_SIZE; j += 1024) acc[j] = 0.0f;
    __syncthreads();
    u32 c = gcount[b], base = gbase[b];
    for (u32 k = threadIdx.x; k < c; k += 1024) {
        u32 rec = __builtin_nontemporal_load(recs + base + k);
        atomicAdd(&acc[rec & (BKT_SIZE - 1)], s[rec >> BKT_BITS]);  // LDS f32 atomic
    }
    __syncthreads();
    int nid0 = b << BKT_BITS;
    float b0 = bb[0];
    for (int j = threadIdx.x; j < BKT_SIZE; j += 1024) {
        int nid = nid0 + j;
        if (nid < N) {
            float z = dinv[nid] * (acc[j] + s[nid]) + b0;
            out[nid] = 1.0f / (1.0f + expf(-z));
        }
    }
}

// ---------------- fallback path ----------------
__global__ void zero_kernel(int* __restrict__ p, int n) {
    int i = blockIdx.x * blockDim.x + threadIdx.x;
    if (i < n) p[i] = 0;
}
__global__ void deg_kernel(const int* __restrict__ dst, int* __restrict__ deg, int E) {
    int i = (blockIdx.x * blockDim.x + threadIdx.x) * 4;
    if (i + 3 < E) {
        int4 d = *reinterpret_cast<const int4*>(dst + i);
        atomicAdd(&deg[d.x], 1); atomicAdd(&deg[d.y], 1);
        atomicAdd(&deg[d.z], 1); atomicAdd(&deg[d.w], 1);
    } else {
        for (int k = i; k < E; ++k) atomicAdd(&deg[dst[k]], 1);
    }
}
__global__ void node_kernel(const float* __restrict__ x, const int* __restrict__ deg,
                            const float* __restrict__ W, float* __restrict__ s,
                            float* __restrict__ dinv, float* __restrict__ acc, int N) {
    int i = blockIdx.x * blockDim.x + threadIdx.x;
    if (i < N) {
        float di = rsqrtf((float)(deg[i] + 1));
        float si = x[i] * W[0] * di;
        dinv[i] = di; s[i] = si; acc[i] = si;
    }
}
__global__ void scatter_kernel(const int* __restrict__ src, const int* __restrict__ dst,
                               const float* __restrict__ s, float* __restrict__ acc, int E) {
    int i = (blockIdx.x * blockDim.x + threadIdx.x) * 4;
    if (i + 3 < E) {
        int4 sv = *reinterpret_cast<const int4*>(src + i);
        int4 dv = *reinterpret_cast<const int4*>(dst + i);
        atomicAdd(&acc[dv.x], s[sv.x]); atomicAdd(&acc[dv.y], s[sv.y]);
        atomicAdd(&acc[dv.z], s[sv.z]); atomicAdd(&acc[dv.w], s[sv.w]);
    } else {
        for (int k = i; k < E; ++k) atomicAdd(&acc[dst[k]], s[src[k]]);
    }
}
__global__ void out_kernel(const float* __restrict__ acc, const float* __restrict__ dinv,
                           const float* __restrict__ b, float* __restrict__ out, int N) {
    int i = blockIdx.x * blockDim.x + threadIdx.x;
    if (i < N) {
        float z = dinv[i] * acc[i] + b[0];
        out[i] = 1.0f / (1.0f + expf(-z));
    }
}

extern "C" void kernel_launch(void* const* d_in, const int* in_sizes, int n_in,
                              void* d_out, int out_size, void* d_ws, size_t ws_size,
                              hipStream_t stream) {
    const int N = in_sizes[0];
    const int E = in_sizes[1] / 2;
    const float* x  = (const float*)d_in[0];
    const int*   ei = (const int*)d_in[1];
    const float* W  = (const float*)d_in[2];
    const float* b  = (const float*)d_in[3];
    float* out = (float*)d_out;

    const int* srcp = ei;
    const int* dstp = ei + E;
    const int T = 256;

    const int NB = (N + BKT_SIZE - 1) >> BKT_BITS;          // 245 for N=1M
    const size_t recCap = (size_t)E + (size_t)NB * 64;      // alignment slack
    // u32-unit layout: recs | gbase | gcursor | gcount | dinv | s
    const size_t need = (recCap + 3 * (size_t)NB + 2 * (size_t)N) * 4;

    if (N <= (1 << 20) && NB <= NBMAX && ws_size >= need) {
        u32* p = (u32*)d_ws;
        u32*   recs    = p;           p += recCap;
        u32*   gbase   = p;           p += NB;
        u32*   gcursor = p;           p += NB;
        u32*   gcount  = p;           p += NB;
        float* dinv    = (float*)p;   p += N;
        float* s       = (float*)p;

        zero_u32<<<1, T, 0, stream>>>(gcount, NB);
        count_kernel<<<1024, T, 0, stream>>>(dstp, gcount, E, NB);
        scan_kernel<<<1, T, 0, stream>>>(gcount, gbase, gcursor, NB);
        bin_kernel<<<(E + TILE - 1) / TILE, BIN_T, 0, stream>>>(srcp, dstp, recs, gcursor, E, NB);
        degnode_kernel<<<NB, 1024, 0, stream>>>(recs, gbase, gcount, x, W, dinv, s, N);
        aggout_kernel<<<NB, 1024, 0, stream>>>(recs, gbase, gcount, s, dinv, b, out, N);
    } else {
        char* ws = (char*)d_ws;
        int*   deg  = (int*)ws;
        float* s    = (float*)(ws + (size_t)N * 4);
        float* dinv = (float*)(ws + (size_t)N * 8);
        float* acc  = (float*)deg;
        const int blocksN = (N + T - 1) / T;
        const int blocksE = ((E + 3) / 4 + T - 1) / T;
        zero_kernel<<<blocksN, T, 0, stream>>>(deg, N);
        deg_kernel<<<blocksE, T, 0, stream>>>(dstp, deg, E);
        node_kernel<<<blocksN, T, 0, stream>>>(x, deg, W, s, dinv, acc, N);
        scatter_kernel<<<blocksE, T, 0, stream>>>(srcp, dstp, s, acc, E);
        out_kernel<<<blocksN, T, 0, stream>>>(acc, dinv, b, out, N);
    }
}